// Round 5
// baseline (453.817 us; speedup 1.0000x reference)
//
#include <hip/hip_runtime.h>

// B=8, C=192, H=W=128, NH=6, HD=32, WS=8, N=64 tokens/window. 2048 windows.
// Round 5: 1024 threads (16 waves) per block -> 4 waves/SIMD latency hiding.
// Same LDS map & phase algorithms as round 4, re-partitioned across 16 waves.
#define SCALEQ 0.17677669529663687f   // 32^-0.5

typedef __bf16 bf16x8 __attribute__((ext_vector_type(8)));
typedef float f32x4 __attribute__((ext_vector_type(4)));

__device__ __forceinline__ float bflo(unsigned int u) { return __uint_as_float(u << 16); }
__device__ __forceinline__ float bfhi(unsigned int u) { return __uint_as_float(u & 0xffff0000u); }
__device__ __forceinline__ unsigned short f2b(float f) {
    unsigned int u = __float_as_uint(f);
    u += 0x7fffu + ((u >> 16) & 1u);      // RNE
    return (unsigned short)(u >> 16);
}

// LDS map (swizzle: byte ^= (row&7)<<4; strides: 384B for [64][192], 128B for [*][64])
//  BUF0   0      xs[64][192] (P1-P2) | o[64][192] (P3-P4) | y[64][192] (P5-P6)
//  QOFF   24576  q[64][192] (P2-P3)  | P: 6 heads x [64][64] bf16, 8KB/head (P4-P5)
//  KOFF   49152  k[64][192] (P2-P3)  | (P heads 3..5)
//  VOFF   73728  v_n[64][192] (P2-P4)
//  VTOFF  98304  v_t[192][64] (P2-P5)
//  BTOFF  122880 bias table 225*6 f32 (5400B)
#define BUF0   0
#define QOFF   24576
#define KOFF   49152
#define POFF   24576
#define VOFF   73728
#define VTOFF  98304
#define BTOFF  122880
#define LDS_BYTES 128280

// d_ws layout (bytes): [0] qkv weights bf16 [576][192] | [221184] proj bf16 [192][192]
//                      | [294912] bias table 225*6 f32
#define WS_WQKV_ELEMS 110592
#define WS_WP_OFF_EL  110592
#define WS_BT_OFF_B   294912

__device__ __forceinline__ bf16x8 ldsf(const char* p) {
    uint4 u = *(const uint4*)p;
    return __builtin_bit_cast(bf16x8, u);
}
__device__ __forceinline__ bf16x8 gldf(const unsigned short* p) {
    uint4 u = *(const uint4*)p;
    return __builtin_bit_cast(bf16x8, u);
}

// ---- prep kernel 1: weights f32 -> bf16 into d_ws ----
__global__ void wprep_kernel(const float* __restrict__ QKw, const float* __restrict__ Vw,
                             const float* __restrict__ Pw, unsigned short* __restrict__ wsb) {
    int i = blockIdx.x * 256 + threadIdx.x;        // 0 .. 147455
    if (i >= 147456) return;
    if (i < WS_WQKV_ELEMS) {
        int r = i / 192, c = i - r * 192;
        float v = (r < 384) ? QKw[r * 192 + c] : Vw[(r - 384) * 192 + c];
        wsb[i] = f2b(v);
    } else {
        int j = i - WS_WQKV_ELEMS;
        wsb[WS_WP_OFF_EL + j] = f2b(Pw[j]);
    }
}

// ---- prep kernel 2: rel-pos bias MLP table (225 x 6) ----
__global__ void bias_table_kernel(const float* __restrict__ Mw1, const float* __restrict__ Mb1,
                                  const float* __restrict__ Mw2, const float* __restrict__ Mb2,
                                  float* __restrict__ bias_out) {
    int t = blockIdx.x * 64 + threadIdx.x;
    if (t >= 225) return;
    int dyi = t / 15, dxi = t % 15;
    float dy = (float)(dyi - 7), dx = (float)(dxi - 7);
    float f0 = copysignf(log1pf(fabsf(dy)), dy);
    float f1 = copysignf(log1pf(fabsf(dx)), dx);
    float a0 = Mb2[0], a1 = Mb2[1], a2 = Mb2[2], a3 = Mb2[3], a4 = Mb2[4], a5 = Mb2[5];
    for (int u = 0; u < 256; ++u) {
        float hv = fmaxf(f0 * Mw1[u] + f1 * Mw1[256 + u] + Mb1[u], 0.0f);
        const float* w2 = Mw2 + u * 6;
        a0 = fmaf(hv, w2[0], a0); a1 = fmaf(hv, w2[1], a1);
        a2 = fmaf(hv, w2[2], a2); a3 = fmaf(hv, w2[3], a3);
        a4 = fmaf(hv, w2[4], a4); a5 = fmaf(hv, w2[5], a5);
    }
    float* bt = bias_out + t * 6;
    bt[0] = a0; bt[1] = a1; bt[2] = a2; bt[3] = a3; bt[4] = a4; bt[5] = a5;
}

__global__ __launch_bounds__(1024)
void fused_win_attn(const float* __restrict__ x,
                    const float* __restrict__ Vb, const float* __restrict__ QKb,
                    const float* __restrict__ Pb,
                    const unsigned short* __restrict__ wqkv,   // bf16 [576][192]
                    const unsigned short* __restrict__ wp,     // bf16 [192][192]
                    const float* __restrict__ bias_g,
                    float* __restrict__ out)
{
    extern __shared__ char smem[];
    const int t   = threadIdx.x;
    const int wv  = t >> 6;           // wave 0..15
    const int l15 = t & 15;
    const int l4  = (t >> 4) & 3;     // (lane>>4) within wave

    const int wid = blockIdx.x;
    const int b   = wid >> 8;
    const int wy  = (wid >> 4) & 15;
    const int wx  = wid & 15;
    const int y0  = wy * 8, x0 = wx * 8;

    const f32x4 zz = {0.0f, 0.0f, 0.0f, 0.0f};

    // ---- P0: bias table global -> LDS ----
    {
        float* bt = (float*)(smem + BTOFF);
        for (int i = t; i < 1350; i += 1024) bt[i] = bias_g[i];
    }

    // ---- P1: load x window -> xs[tok][ch] bf16 swizzled (3072 float4 / 1024 thr) ----
    {
        const float* xb = x + (size_t)b * 192 * 16384;
        #pragma unroll
        for (int i = 0; i < 3; ++i) {
            int idx = t + 1024 * i;
            int c = idx >> 4, sub = idx & 15;
            int r = sub >> 1, hf = sub & 1;
            float4 v4 = *(const float4*)(xb + c * 16384 + (y0 + r) * 128 + x0 + hf * 4);
            int n0 = r * 8 + hf * 4;
            unsigned short sv[4] = {f2b(v4.x), f2b(v4.y), f2b(v4.z), f2b(v4.w)};
            #pragma unroll
            for (int e = 0; e < 4; ++e) {
                int n = n0 + e;
                *(unsigned short*)(smem + BUF0 + ((n * 384 + c * 2) ^ ((n & 7) << 4))) = sv[e];
            }
        }
    }
    __syncthreads();

    // ---- P2: qkv GEMM via MFMA. wave (wcol 0..3, wrow 0..3): cols [144*wcol,+144), toks [16*wrow,+16) ----
    {
        const int wcol = wv & 3, wrow = wv >> 2;
        bf16x8 afr[6];
        #pragma unroll
        for (int ks = 0; ks < 6; ++ks) {
            int row = wrow * 16 + l15;
            afr[ks] = ldsf(smem + BUF0 + ((row * 384 + ks * 64 + l4 * 16) ^ ((row & 7) << 4)));
        }
        #pragma unroll
        for (int chunk = 0; chunk < 3; ++chunk) {
            f32x4 acc[3];
            #pragma unroll
            for (int j = 0; j < 3; ++j) acc[j] = zz;
            #pragma unroll
            for (int ks = 0; ks < 6; ++ks) {
                bf16x8 bfr[3];
                #pragma unroll
                for (int j = 0; j < 3; ++j) {
                    int ob = wcol * 144 + chunk * 48 + j * 16;
                    bfr[j] = gldf(wqkv + (size_t)(ob + l15) * 192 + ks * 32 + l4 * 8);
                }
                #pragma unroll
                for (int j = 0; j < 3; ++j)
                    acc[j] = __builtin_amdgcn_mfma_f32_16x16x32_bf16(afr[ks], bfr[j], acc[j], 0, 0, 0);
            }
            // epilogue: +bias, scale q, write q/k/v (v also transposed)
            #pragma unroll
            for (int j = 0; j < 3; ++j) {
                int ob  = wcol * 144 + chunk * 48 + j * 16;
                int och = ob + l15;
                float bv = (ob < 384) ? QKb[och] : Vb[och - 384];
                #pragma unroll
                for (int rr = 0; rr < 4; ++rr) {
                    float val = acc[j][rr] + bv;
                    int tok = wrow * 16 + l4 * 4 + rr;
                    if (ob < 192) {
                        *(unsigned short*)(smem + QOFF + ((tok * 384 + och * 2) ^ ((tok & 7) << 4))) = f2b(val * SCALEQ);
                    } else if (ob < 384) {
                        int ch = och - 192;
                        *(unsigned short*)(smem + KOFF + ((tok * 384 + ch * 2) ^ ((tok & 7) << 4))) = f2b(val);
                    } else {
                        int ch = och - 384;
                        unsigned short hv = f2b(val);
                        *(unsigned short*)(smem + VOFF  + ((tok * 384 + ch * 2) ^ ((tok & 7) << 4))) = hv;
                        *(unsigned short*)(smem + VTOFF + ((ch * 128 + tok * 2) ^ ((ch & 7) << 4))) = hv;
                    }
                }
            }
        }
    }
    __syncthreads();

    // ---- P3: 8x8 circular conv, register-blocked. 768 threads: (rn 0..7, 96 x 2ch) ----
    if (t < 768) {
        const int rn = t / 96, cc = t % 96;
        const int c0b = cc * 4;               // byte offset of 2-ch chunk
        float acc[8][2];
        #pragma unroll
        for (int cn = 0; cn < 8; ++cn) { acc[cn][0] = 0.0f; acc[cn][1] = 0.0f; }

        #pragma unroll
        for (int kh = 0; kh < 2; ++kh) {
            unsigned int karr[32];
            #pragma unroll
            for (int m = 0; m < 32; ++m) {
                int row = kh * 32 + m;
                karr[m] = *(const unsigned int*)(smem + KOFF + ((row * 384 + c0b) ^ ((row & 7) << 4)));
            }
            #pragma unroll
            for (int mrl = 0; mrl < 4; ++mrl) {
                const int mr = kh * 4 + mrl;
                float kf[8][2];
                #pragma unroll
                for (int mc = 0; mc < 8; ++mc) {
                    unsigned int kv = karr[mrl * 8 + mc];
                    kf[mc][0] = bflo(kv); kf[mc][1] = bfhi(kv);
                }
                const int npr = (rn - mr) & 7;
                #pragma unroll
                for (int npc = 0; npc < 8; ++npc) {
                    int np = npr * 8 + npc;
                    unsigned int qv = *(const unsigned int*)(smem + QOFF + ((np * 384 + c0b) ^ ((np & 7) << 4)));
                    float qf0 = bflo(qv), qf1 = bfhi(qv);
                    #pragma unroll
                    for (int mc = 0; mc < 8; ++mc) {
                        int cn = (npc + mc) & 7;
                        acc[cn][0] = fmaf(qf0, kf[mc][0], acc[cn][0]);
                        acc[cn][1] = fmaf(qf1, kf[mc][1], acc[cn][1]);
                    }
                }
            }
        }
        #pragma unroll
        for (int cn = 0; cn < 8; ++cn) {
            int n = rn * 8 + cn;
            unsigned int pk = (unsigned int)f2b(acc[cn][0]) | ((unsigned int)f2b(acc[cn][1]) << 16);
            *(unsigned int*)(smem + BUF0 + ((n * 384 + c0b) ^ ((n & 7) << 4))) = pk;
        }
    }
    __syncthreads();

    // ---- P4: S = o.v^T + bias, softmax, P -> LDS. 24 units (h, mt) over 16 waves ----
    {
        const float* bt = (const float*)(smem + BTOFF);
        for (int u = wv; u < 24; u += 16) {
            int h = u >> 2, mt = u & 3;
            int arow = mt * 16 + l15;
            bf16x8 afr = ldsf(smem + BUF0 + ((arow * 384 + h * 64 + l4 * 16) ^ ((arow & 7) << 4)));
            f32x4 acc[4];
            #pragma unroll
            for (int nt = 0; nt < 4; ++nt) {
                int brow = nt * 16 + l15;
                bf16x8 bfr = ldsf(smem + VOFF + ((brow * 384 + h * 64 + l4 * 16) ^ ((brow & 7) << 4)));
                acc[nt] = __builtin_amdgcn_mfma_f32_16x16x32_bf16(afr, bfr, zz, 0, 0, 0);
            }
            float s[4][4];
            #pragma unroll
            for (int nt = 0; nt < 4; ++nt) {
                int m = nt * 16 + l15;
                int myr = m >> 3, myc = m & 7;
                #pragma unroll
                for (int rr = 0; rr < 4; ++rr) {
                    int n = mt * 16 + l4 * 4 + rr;
                    int dy = (n >> 3) - myr + 7, dx = (n & 7) - myc + 7;
                    s[nt][rr] = acc[nt][rr] + bt[(dy * 15 + dx) * 6 + h];
                }
            }
            float inv[4];
            #pragma unroll
            for (int rr = 0; rr < 4; ++rr) {
                float m0 = fmaxf(fmaxf(s[0][rr], s[1][rr]), fmaxf(s[2][rr], s[3][rr]));
                m0 = fmaxf(m0, __shfl_xor(m0, 1));
                m0 = fmaxf(m0, __shfl_xor(m0, 2));
                m0 = fmaxf(m0, __shfl_xor(m0, 4));
                m0 = fmaxf(m0, __shfl_xor(m0, 8));
                float sm = 0.0f;
                #pragma unroll
                for (int nt = 0; nt < 4; ++nt) {
                    float p = __expf(s[nt][rr] - m0);
                    s[nt][rr] = p; sm += p;
                }
                sm += __shfl_xor(sm, 1); sm += __shfl_xor(sm, 2);
                sm += __shfl_xor(sm, 4); sm += __shfl_xor(sm, 8);
                inv[rr] = 1.0f / sm;
            }
            #pragma unroll
            for (int nt = 0; nt < 4; ++nt)
                #pragma unroll
                for (int rr = 0; rr < 4; ++rr) {
                    int n = mt * 16 + l4 * 4 + rr, m = nt * 16 + l15;
                    *(unsigned short*)(smem + POFF + h * 8192 + ((n * 128 + m * 2) ^ ((n & 7) << 4)))
                        = f2b(s[nt][rr] * inv[rr]);
                }
        }
    }
    __syncthreads();

    // ---- P5: Y = P.v  (units over 16 waves) -> y[tok][ch] in BUF0 ----
    {
        for (int u = wv; u < 24; u += 16) {
            int h = u >> 2, mt = u & 3;
            bf16x8 pa[2];
            #pragma unroll
            for (int ks = 0; ks < 2; ++ks) {
                int row = mt * 16 + l15;
                pa[ks] = ldsf(smem + POFF + h * 8192 + ((row * 128 + ks * 64 + l4 * 16) ^ ((row & 7) << 4)));
            }
            f32x4 acc[2];
            acc[0] = zz; acc[1] = zz;
            #pragma unroll
            for (int dt = 0; dt < 2; ++dt)
                #pragma unroll
                for (int ks = 0; ks < 2; ++ks) {
                    int ch = h * 32 + dt * 16 + l15;
                    bf16x8 bfr = ldsf(smem + VTOFF + ((ch * 128 + ks * 64 + l4 * 16) ^ ((ch & 7) << 4)));
                    acc[dt] = __builtin_amdgcn_mfma_f32_16x16x32_bf16(pa[ks], bfr, acc[dt], 0, 0, 0);
                }
            #pragma unroll
            for (int dt = 0; dt < 2; ++dt)
                #pragma unroll
                for (int rr = 0; rr < 4; ++rr) {
                    int tok = mt * 16 + l4 * 4 + rr;
                    int ch  = h * 32 + dt * 16 + l15;
                    *(unsigned short*)(smem + BUF0 + ((tok * 384 + ch * 2) ^ ((tok & 7) << 4))) = f2b(acc[dt][rr]);
                }
        }
    }
    __syncthreads();

    // ---- P6: proj, transposed: OUTt[oc][tok] = Pw . y^T. wave (wc 0..3, wr 0..3) ----
    {
        const int wc = wv & 3, wr = wv >> 2;
        f32x4 acc[3];
        #pragma unroll
        for (int jt = 0; jt < 3; ++jt) acc[jt] = zz;

        #pragma unroll
        for (int ks = 0; ks < 6; ++ks) {
            int tok = wr * 16 + l15;
            bf16x8 bfr = ldsf(smem + BUF0 + ((tok * 384 + ks * 64 + l4 * 16) ^ ((tok & 7) << 4)));
            #pragma unroll
            for (int jt = 0; jt < 3; ++jt) {
                int oc = wc * 48 + jt * 16;
                bf16x8 afr = gldf(wp + (size_t)(oc + l15) * 192 + ks * 32 + l4 * 8);
                acc[jt] = __builtin_amdgcn_mfma_f32_16x16x32_bf16(afr, bfr, acc[jt], 0, 0, 0);
            }
        }
        #pragma unroll
        for (int jt = 0; jt < 3; ++jt)
            #pragma unroll
            for (int rr = 0; rr < 4; ++rr) {
                int oc = wc * 48 + jt * 16 + l4 * 4 + rr;
                float pb = Pb[oc];
                float* obase = out + (size_t)(b * 192 + oc) * 16384;
                int tok = wr * 16 + l15;
                obase[(y0 + (tok >> 3)) * 128 + x0 + (tok & 7)] = acc[jt][rr] + pb;
            }
    }
}

extern "C" void kernel_launch(void* const* d_in, const int* in_sizes, int n_in,
                              void* d_out, int out_size, void* d_ws, size_t ws_size,
                              hipStream_t stream) {
    const float* x   = (const float*)d_in[0];
    const float* Vw  = (const float*)d_in[1];
    const float* Vb  = (const float*)d_in[2];
    const float* QKw = (const float*)d_in[3];
    const float* QKb = (const float*)d_in[4];
    const float* Pw  = (const float*)d_in[5];
    const float* Pb  = (const float*)d_in[6];
    const float* Mw1 = (const float*)d_in[7];
    const float* Mb1 = (const float*)d_in[8];
    const float* Mw2 = (const float*)d_in[9];
    const float* Mb2 = (const float*)d_in[10];
    float* outp = (float*)d_out;

    unsigned short* wsb  = (unsigned short*)d_ws;              // bf16 weights
    float* biasw = (float*)((char*)d_ws + WS_BT_OFF_B);        // bias table

    wprep_kernel<<<dim3(576), dim3(256), 0, stream>>>(QKw, Vw, Pw, wsb);
    bias_table_kernel<<<dim3(4), dim3(64), 0, stream>>>(Mw1, Mb1, Mw2, Mb2, biasw);

    (void)hipFuncSetAttribute((const void*)fused_win_attn,
                              hipFuncAttributeMaxDynamicSharedMemorySize, LDS_BYTES);
    fused_win_attn<<<dim3(2048), dim3(1024), LDS_BYTES, stream>>>(
        x, Vb, QKb, Pb, wsb, wsb + WS_WP_OFF_EL, biasw, outp);
}

// Round 6
// 333.660 us; speedup vs baseline: 1.3601x; 1.3601x over previous
//
#include <hip/hip_runtime.h>

// B=8, C=192, H=W=128, NH=6, HD=32, WS=8, N=64 tokens/window. 2048 windows.
// Round 6: round-4 partitioning (512 thr) + register batch-prefetch of weights
// in P2/P6 + XCD-aware window swizzle + f32x2 packed conv math.
#define SCALEQ 0.17677669529663687f   // 32^-0.5

typedef __bf16 bf16x8 __attribute__((ext_vector_type(8)));
typedef float f32x4 __attribute__((ext_vector_type(4)));
typedef float f32x2 __attribute__((ext_vector_type(2)));

__device__ __forceinline__ float bflo(unsigned int u) { return __uint_as_float(u << 16); }
__device__ __forceinline__ float bfhi(unsigned int u) { return __uint_as_float(u & 0xffff0000u); }
__device__ __forceinline__ f32x2 b2x2(unsigned int u) {
    f32x2 r; r[0] = bflo(u); r[1] = bfhi(u); return r;
}
__device__ __forceinline__ unsigned short f2b(float f) {
    unsigned int u = __float_as_uint(f);
    u += 0x7fffu + ((u >> 16) & 1u);      // RNE
    return (unsigned short)(u >> 16);
}

// LDS map (swizzle: byte ^= (row&7)<<4; strides: 384B for [64][192], 128B for [*][64])
//  BUF0   0      xs[64][192] (P1-P2) | o[64][192] (P3-P4) | y[64][192] (P5-P6)
//  QOFF   24576  q[64][192] (P2-P3)  | P: 6 heads x [64][64] bf16, 8KB/head (P4-P5)
//  KOFF   49152  k[64][192] (P2-P3)  | (P heads 3..5)
//  VOFF   73728  v_n[64][192] (P2-P4)
//  VTOFF  98304  v_t[192][64] (P2-P5)
//  BTOFF  122880 bias table 225*6 f32 (5400B)
#define BUF0   0
#define QOFF   24576
#define KOFF   49152
#define POFF   24576
#define VOFF   73728
#define VTOFF  98304
#define BTOFF  122880
#define LDS_BYTES 128280

// d_ws layout (bytes): [0] qkv weights bf16 [576][192] | [221184] proj bf16 [192][192]
//                      | [294912] bias table 225*6 f32
#define WS_WQKV_ELEMS 110592
#define WS_WP_OFF_EL  110592
#define WS_BT_OFF_B   294912

__device__ __forceinline__ bf16x8 ldsf(const char* p) {
    uint4 u = *(const uint4*)p;
    return __builtin_bit_cast(bf16x8, u);
}
__device__ __forceinline__ bf16x8 gldf(const unsigned short* p) {
    uint4 u = *(const uint4*)p;
    return __builtin_bit_cast(bf16x8, u);
}

// ---- prep kernel 1: weights f32 -> bf16 into d_ws ----
__global__ void wprep_kernel(const float* __restrict__ QKw, const float* __restrict__ Vw,
                             const float* __restrict__ Pw, unsigned short* __restrict__ wsb) {
    int i = blockIdx.x * 256 + threadIdx.x;        // 0 .. 147455
    if (i >= 147456) return;
    if (i < WS_WQKV_ELEMS) {
        int r = i / 192, c = i - r * 192;
        float v = (r < 384) ? QKw[r * 192 + c] : Vw[(r - 384) * 192 + c];
        wsb[i] = f2b(v);
    } else {
        int j = i - WS_WQKV_ELEMS;
        wsb[WS_WP_OFF_EL + j] = f2b(Pw[j]);
    }
}

// ---- prep kernel 2: rel-pos bias MLP table (225 x 6) ----
__global__ void bias_table_kernel(const float* __restrict__ Mw1, const float* __restrict__ Mb1,
                                  const float* __restrict__ Mw2, const float* __restrict__ Mb2,
                                  float* __restrict__ bias_out) {
    int t = blockIdx.x * 64 + threadIdx.x;
    if (t >= 225) return;
    int dyi = t / 15, dxi = t % 15;
    float dy = (float)(dyi - 7), dx = (float)(dxi - 7);
    float f0 = copysignf(log1pf(fabsf(dy)), dy);
    float f1 = copysignf(log1pf(fabsf(dx)), dx);
    float a0 = Mb2[0], a1 = Mb2[1], a2 = Mb2[2], a3 = Mb2[3], a4 = Mb2[4], a5 = Mb2[5];
    for (int u = 0; u < 256; ++u) {
        float hv = fmaxf(f0 * Mw1[u] + f1 * Mw1[256 + u] + Mb1[u], 0.0f);
        const float* w2 = Mw2 + u * 6;
        a0 = fmaf(hv, w2[0], a0); a1 = fmaf(hv, w2[1], a1);
        a2 = fmaf(hv, w2[2], a2); a3 = fmaf(hv, w2[3], a3);
        a4 = fmaf(hv, w2[4], a4); a5 = fmaf(hv, w2[5], a5);
    }
    float* bt = bias_out + t * 6;
    bt[0] = a0; bt[1] = a1; bt[2] = a2; bt[3] = a3; bt[4] = a4; bt[5] = a5;
}

__global__ __launch_bounds__(512, 2)
void fused_win_attn(const float* __restrict__ x,
                    const float* __restrict__ Vb, const float* __restrict__ QKb,
                    const float* __restrict__ Pb,
                    const unsigned short* __restrict__ wqkv,   // bf16 [576][192]
                    const unsigned short* __restrict__ wp,     // bf16 [192][192]
                    const float* __restrict__ bias_g,
                    float* __restrict__ out)
{
    extern __shared__ char smem[];
    const int t   = threadIdx.x;
    const int wv  = t >> 6;           // wave 0..7
    const int l15 = t & 15;
    const int l4  = (t >> 4) & 3;     // (lane>>4) within wave

    // XCD-aware swizzle: consecutive windows (which share x cachelines) on the
    // same XCD. 2048 blocks, 8 XCDs, 2048%8==0 -> bijective.
    const int wid = ((blockIdx.x & 7) << 8) | (blockIdx.x >> 3);
    const int b   = wid >> 8;
    const int wy  = (wid >> 4) & 15;
    const int wx  = wid & 15;
    const int y0  = wy * 8, x0 = wx * 8;

    const f32x4 zz = {0.0f, 0.0f, 0.0f, 0.0f};

    // ---- P0: bias table global -> LDS ----
    {
        float* bt = (float*)(smem + BTOFF);
        for (int i = t; i < 1350; i += 512) bt[i] = bias_g[i];
    }

    // ---- P1: load x window -> xs[tok][ch] bf16 swizzled (3072 float4 / 512 thr) ----
    {
        const float* xb = x + (size_t)b * 192 * 16384;
        #pragma unroll
        for (int i = 0; i < 6; ++i) {
            int idx = t + 512 * i;
            int c = idx >> 4, sub = idx & 15;
            int r = sub >> 1, hf = sub & 1;
            float4 v4 = *(const float4*)(xb + c * 16384 + (y0 + r) * 128 + x0 + hf * 4);
            int n0 = r * 8 + hf * 4;
            unsigned short sv[4] = {f2b(v4.x), f2b(v4.y), f2b(v4.z), f2b(v4.w)};
            #pragma unroll
            for (int e = 0; e < 4; ++e) {
                int n = n0 + e;
                *(unsigned short*)(smem + BUF0 + ((n * 384 + c * 2) ^ ((n & 7) << 4))) = sv[e];
            }
        }
    }
    __syncthreads();

    // ---- P2: qkv GEMM via MFMA. wave (wcol,wrow): cols [144*wcol,+144), toks [32*wrow,+32) ----
    // Weight fragments batch-prefetched per chunk (18 b128 loads issued before MFMAs).
    {
        const int wcol = wv & 3, wrow = wv >> 2;
        bf16x8 afr[6][2];
        #pragma unroll
        for (int ks = 0; ks < 6; ++ks)
            #pragma unroll
            for (int mtl = 0; mtl < 2; ++mtl) {
                int row = (wrow * 2 + mtl) * 16 + l15;
                afr[ks][mtl] = ldsf(smem + BUF0 + ((row * 384 + ks * 64 + l4 * 16) ^ ((row & 7) << 4)));
            }
        #pragma unroll
        for (int chunk = 0; chunk < 3; ++chunk) {
            bf16x8 bw[3][6];
            #pragma unroll
            for (int j = 0; j < 3; ++j) {
                int ob = wcol * 144 + chunk * 48 + j * 16;
                const unsigned short* wr = wqkv + (size_t)(ob + l15) * 192 + l4 * 8;
                #pragma unroll
                for (int ks = 0; ks < 6; ++ks) bw[j][ks] = gldf(wr + ks * 32);
            }
            f32x4 acc[3][2];
            #pragma unroll
            for (int j = 0; j < 3; ++j) { acc[j][0] = zz; acc[j][1] = zz; }
            #pragma unroll
            for (int ks = 0; ks < 6; ++ks)
                #pragma unroll
                for (int j = 0; j < 3; ++j)
                    #pragma unroll
                    for (int mtl = 0; mtl < 2; ++mtl)
                        acc[j][mtl] = __builtin_amdgcn_mfma_f32_16x16x32_bf16(afr[ks][mtl], bw[j][ks], acc[j][mtl], 0, 0, 0);
            // epilogue: +bias, scale q, write q/k/v (v also transposed)
            #pragma unroll
            for (int j = 0; j < 3; ++j) {
                int ob  = wcol * 144 + chunk * 48 + j * 16;
                int och = ob + l15;
                float bv = (ob < 384) ? QKb[och] : Vb[och - 384];
                #pragma unroll
                for (int mtl = 0; mtl < 2; ++mtl) {
                    #pragma unroll
                    for (int rr = 0; rr < 4; ++rr) {
                        float val = acc[j][mtl][rr] + bv;
                        int tok = (wrow * 2 + mtl) * 16 + l4 * 4 + rr;
                        if (ob < 192) {
                            *(unsigned short*)(smem + QOFF + ((tok * 384 + och * 2) ^ ((tok & 7) << 4))) = f2b(val * SCALEQ);
                        } else if (ob < 384) {
                            int ch = och - 192;
                            *(unsigned short*)(smem + KOFF + ((tok * 384 + ch * 2) ^ ((tok & 7) << 4))) = f2b(val);
                        } else {
                            int ch = och - 384;
                            unsigned short hv = f2b(val);
                            *(unsigned short*)(smem + VOFF  + ((tok * 384 + ch * 2) ^ ((tok & 7) << 4))) = hv;
                            *(unsigned short*)(smem + VTOFF + ((ch * 128 + tok * 2) ^ ((ch & 7) << 4))) = hv;
                        }
                    }
                }
            }
        }
    }
    __syncthreads();

    // ---- P3: 8x8 circular conv, register-blocked, f32x2 packed. 384 threads ----
    if (t < 384) {
        const int rn = t / 48, cc = t % 48;
        const int c0b = cc * 8;               // byte offset of 4-ch chunk
        f32x2 acc[8][2];
        #pragma unroll
        for (int cn = 0; cn < 8; ++cn) {
            acc[cn][0] = (f32x2){0.0f, 0.0f};
            acc[cn][1] = (f32x2){0.0f, 0.0f};
        }

        #pragma unroll
        for (int kh = 0; kh < 2; ++kh) {
            uint2 karr[32];
            #pragma unroll
            for (int m = 0; m < 32; ++m) {
                int row = kh * 32 + m;
                karr[m] = *(const uint2*)(smem + KOFF + ((row * 384 + c0b) ^ ((row & 7) << 4)));
            }
            #pragma unroll
            for (int mrl = 0; mrl < 4; ++mrl) {
                const int mr = kh * 4 + mrl;
                f32x2 kf[8][2];
                #pragma unroll
                for (int mc = 0; mc < 8; ++mc) {
                    uint2 kv = karr[mrl * 8 + mc];
                    kf[mc][0] = b2x2(kv.x); kf[mc][1] = b2x2(kv.y);
                }
                const int npr = (rn - mr) & 7;
                #pragma unroll
                for (int npc = 0; npc < 8; ++npc) {
                    int np = npr * 8 + npc;
                    uint2 qv = *(const uint2*)(smem + QOFF + ((np * 384 + c0b) ^ ((np & 7) << 4)));
                    f32x2 qf0 = b2x2(qv.x), qf1 = b2x2(qv.y);
                    #pragma unroll
                    for (int mc = 0; mc < 8; ++mc) {
                        int cn = (npc + mc) & 7;
                        acc[cn][0] = qf0 * kf[mc][0] + acc[cn][0];
                        acc[cn][1] = qf1 * kf[mc][1] + acc[cn][1];
                    }
                }
            }
        }
        #pragma unroll
        for (int cn = 0; cn < 8; ++cn) {
            int n = rn * 8 + cn;
            uint2 pk;
            pk.x = (unsigned int)f2b(acc[cn][0][0]) | ((unsigned int)f2b(acc[cn][0][1]) << 16);
            pk.y = (unsigned int)f2b(acc[cn][1][0]) | ((unsigned int)f2b(acc[cn][1][1]) << 16);
            *(uint2*)(smem + BUF0 + ((n * 384 + c0b) ^ ((n & 7) << 4))) = pk;
        }
    }
    __syncthreads();

    // ---- P4: S = o.v^T + bias, softmax, P -> LDS. 24 units (h, mt), 3 per wave ----
    {
        const float* bt = (const float*)(smem + BTOFF);
        for (int i = 0; i < 3; ++i) {
            int u = wv * 3 + i;
            int h = u >> 2, mt = u & 3;
            int arow = mt * 16 + l15;
            bf16x8 afr = ldsf(smem + BUF0 + ((arow * 384 + h * 64 + l4 * 16) ^ ((arow & 7) << 4)));
            f32x4 acc[4];
            #pragma unroll
            for (int nt = 0; nt < 4; ++nt) {
                int brow = nt * 16 + l15;
                bf16x8 bfr = ldsf(smem + VOFF + ((brow * 384 + h * 64 + l4 * 16) ^ ((brow & 7) << 4)));
                acc[nt] = __builtin_amdgcn_mfma_f32_16x16x32_bf16(afr, bfr, zz, 0, 0, 0);
            }
            float s[4][4];
            #pragma unroll
            for (int nt = 0; nt < 4; ++nt) {
                int m = nt * 16 + l15;
                int myr = m >> 3, myc = m & 7;
                #pragma unroll
                for (int rr = 0; rr < 4; ++rr) {
                    int n = mt * 16 + l4 * 4 + rr;
                    int dy = (n >> 3) - myr + 7, dx = (n & 7) - myc + 7;
                    s[nt][rr] = acc[nt][rr] + bt[(dy * 15 + dx) * 6 + h];
                }
            }
            float inv[4];
            #pragma unroll
            for (int rr = 0; rr < 4; ++rr) {
                float m0 = fmaxf(fmaxf(s[0][rr], s[1][rr]), fmaxf(s[2][rr], s[3][rr]));
                m0 = fmaxf(m0, __shfl_xor(m0, 1));
                m0 = fmaxf(m0, __shfl_xor(m0, 2));
                m0 = fmaxf(m0, __shfl_xor(m0, 4));
                m0 = fmaxf(m0, __shfl_xor(m0, 8));
                float sm = 0.0f;
                #pragma unroll
                for (int nt = 0; nt < 4; ++nt) {
                    float p = __expf(s[nt][rr] - m0);
                    s[nt][rr] = p; sm += p;
                }
                sm += __shfl_xor(sm, 1); sm += __shfl_xor(sm, 2);
                sm += __shfl_xor(sm, 4); sm += __shfl_xor(sm, 8);
                inv[rr] = 1.0f / sm;
            }
            #pragma unroll
            for (int nt = 0; nt < 4; ++nt)
                #pragma unroll
                for (int rr = 0; rr < 4; ++rr) {
                    int n = mt * 16 + l4 * 4 + rr, m = nt * 16 + l15;
                    *(unsigned short*)(smem + POFF + h * 8192 + ((n * 128 + m * 2) ^ ((n & 7) << 4)))
                        = f2b(s[nt][rr] * inv[rr]);
                }
        }
    }
    __syncthreads();

    // ---- P5: Y = P.v  (3 units per wave) -> y[tok][ch] in BUF0 ----
    {
        for (int i = 0; i < 3; ++i) {
            int u = wv * 3 + i;
            int h = u >> 2, mt = u & 3;
            bf16x8 pa[2];
            #pragma unroll
            for (int ks = 0; ks < 2; ++ks) {
                int row = mt * 16 + l15;
                pa[ks] = ldsf(smem + POFF + h * 8192 + ((row * 128 + ks * 64 + l4 * 16) ^ ((row & 7) << 4)));
            }
            f32x4 acc[2];
            acc[0] = zz; acc[1] = zz;
            #pragma unroll
            for (int dt = 0; dt < 2; ++dt)
                #pragma unroll
                for (int ks = 0; ks < 2; ++ks) {
                    int ch = h * 32 + dt * 16 + l15;
                    bf16x8 bfr = ldsf(smem + VTOFF + ((ch * 128 + ks * 64 + l4 * 16) ^ ((ch & 7) << 4)));
                    acc[dt] = __builtin_amdgcn_mfma_f32_16x16x32_bf16(pa[ks], bfr, acc[dt], 0, 0, 0);
                }
            #pragma unroll
            for (int dt = 0; dt < 2; ++dt)
                #pragma unroll
                for (int rr = 0; rr < 4; ++rr) {
                    int tok = mt * 16 + l4 * 4 + rr;
                    int ch  = h * 32 + dt * 16 + l15;
                    *(unsigned short*)(smem + BUF0 + ((tok * 384 + ch * 2) ^ ((tok & 7) << 4))) = f2b(acc[dt][rr]);
                }
        }
    }
    __syncthreads();

    // ---- P6: proj, transposed: OUTt[oc][tok] = Pw . y^T. wave (wc,wr) ----
    // Proj weight fragments batch-prefetched (18 b128 loads) before the loop.
    {
        const int wc = wv & 3, wr = wv >> 2;
        bf16x8 wfr[3][6];
        #pragma unroll
        for (int jt = 0; jt < 3; ++jt) {
            int oc = wc * 48 + jt * 16;
            const unsigned short* wr_ = wp + (size_t)(oc + l15) * 192 + l4 * 8;
            #pragma unroll
            for (int ks = 0; ks < 6; ++ks) wfr[jt][ks] = gldf(wr_ + ks * 32);
        }
        f32x4 acc[3][2];
        #pragma unroll
        for (int jt = 0; jt < 3; ++jt) { acc[jt][0] = zz; acc[jt][1] = zz; }

        #pragma unroll
        for (int ks = 0; ks < 6; ++ks) {
            bf16x8 bfr[2];
            #pragma unroll
            for (int ntl = 0; ntl < 2; ++ntl) {
                int tok = (wr * 2 + ntl) * 16 + l15;
                bfr[ntl] = ldsf(smem + BUF0 + ((tok * 384 + ks * 64 + l4 * 16) ^ ((tok & 7) << 4)));
            }
            #pragma unroll
            for (int jt = 0; jt < 3; ++jt)
                #pragma unroll
                for (int ntl = 0; ntl < 2; ++ntl)
                    acc[jt][ntl] = __builtin_amdgcn_mfma_f32_16x16x32_bf16(wfr[jt][ks], bfr[ntl], acc[jt][ntl], 0, 0, 0);
        }
        #pragma unroll
        for (int jt = 0; jt < 3; ++jt)
            #pragma unroll
            for (int rr = 0; rr < 4; ++rr) {
                int oc = wc * 48 + jt * 16 + l4 * 4 + rr;
                float pb = Pb[oc];
                float* obase = out + (size_t)(b * 192 + oc) * 16384;
                #pragma unroll
                for (int ntl = 0; ntl < 2; ++ntl) {
                    int tok = (wr * 2 + ntl) * 16 + l15;
                    obase[(y0 + (tok >> 3)) * 128 + x0 + (tok & 7)] = acc[jt][ntl][rr] + pb;
                }
            }
    }
}

extern "C" void kernel_launch(void* const* d_in, const int* in_sizes, int n_in,
                              void* d_out, int out_size, void* d_ws, size_t ws_size,
                              hipStream_t stream) {
    const float* x   = (const float*)d_in[0];
    const float* Vw  = (const float*)d_in[1];
    const float* Vb  = (const float*)d_in[2];
    const float* QKw = (const float*)d_in[3];
    const float* QKb = (const float*)d_in[4];
    const float* Pw  = (const float*)d_in[5];
    const float* Pb  = (const float*)d_in[6];
    const float* Mw1 = (const float*)d_in[7];
    const float* Mb1 = (const float*)d_in[8];
    const float* Mw2 = (const float*)d_in[9];
    const float* Mb2 = (const float*)d_in[10];
    float* outp = (float*)d_out;

    unsigned short* wsb  = (unsigned short*)d_ws;              // bf16 weights
    float* biasw = (float*)((char*)d_ws + WS_BT_OFF_B);        // bias table

    wprep_kernel<<<dim3(576), dim3(256), 0, stream>>>(QKw, Vw, Pw, wsb);
    bias_table_kernel<<<dim3(4), dim3(64), 0, stream>>>(Mw1, Mb1, Mw2, Mb2, biasw);

    (void)hipFuncSetAttribute((const void*)fused_win_attn,
                              hipFuncAttributeMaxDynamicSharedMemorySize, LDS_BYTES);
    fused_win_attn<<<dim3(2048), dim3(512), LDS_BYTES, stream>>>(
        x, Vb, QKb, Pb, wsb, wsb + WS_WP_OFF_EL, biasw, outp);
}

// Round 8
// 299.174 us; speedup vs baseline: 1.5169x; 1.1153x over previous
//
#include <hip/hip_runtime.h>

// B=8, C=192, H=W=128, NH=6, HD=32, WS=8, N=64 tokens/window. 2048 windows.
// Round 8: round-7 structure (79 KB LDS -> 2 blocks/CU) with the P5 shuffle
// fixed: two pulls + dst-side (l4&2) register select (src-side select was the
// round-7 bug: __shfl evaluates the value expr in the SOURCE lane, and dst
// lanes l4=0/l4=2 share a source but need different mt registers).
#define SCALEQ 0.17677669529663687f   // 32^-0.5

typedef __bf16 bf16x8 __attribute__((ext_vector_type(8)));
typedef float f32x4 __attribute__((ext_vector_type(4)));
typedef float f32x2 __attribute__((ext_vector_type(2)));

__device__ __forceinline__ float bflo(unsigned int u) { return __uint_as_float(u << 16); }
__device__ __forceinline__ float bfhi(unsigned int u) { return __uint_as_float(u & 0xffff0000u); }
__device__ __forceinline__ f32x2 b2x2(unsigned int u) {
    f32x2 r; r[0] = bflo(u); r[1] = bfhi(u); return r;
}
__device__ __forceinline__ unsigned short f2b(float f) {
    unsigned int u = __float_as_uint(f);
    u += 0x7fffu + ((u >> 16) & 1u);      // RNE
    return (unsigned short)(u >> 16);
}
__device__ __forceinline__ unsigned int pk2(float a, float b) {
    return (unsigned int)f2b(a) | ((unsigned int)f2b(b) << 16);
}

// LDS: 3 x 24 KB regions (swizzle byte ^= (row&7)<<4), time-multiplexed:
//  RA 0      xs[64][192] (P1-hoist) | q[64][192] (P2-P3) | v_n[64][192] (P3b-P4)
//  RB 24576  k[64][192]  (P2-P3)    | v_t[192][64] (P3b-P5)
//  RC 49152  o[64][192]  (P3-P4)    | y[64][192]  (P5-P6)
//  BTOFF 73728 bias table 225*6 f32 (5400 B)
#define RA     0
#define RB     24576
#define RC     49152
#define BTOFF  73728
#define LDS_BYTES 79128

// d_ws layout (bytes): [0] qkv weights bf16 [576][192] | [221184] proj bf16 [192][192]
//                      | [294912] bias table 225*6 f32
#define WS_WQKV_ELEMS 110592
#define WS_WP_OFF_EL  110592
#define WS_BT_OFF_B   294912

__device__ __forceinline__ bf16x8 ldsf(const char* p) {
    uint4 u = *(const uint4*)p;
    return __builtin_bit_cast(bf16x8, u);
}
__device__ __forceinline__ bf16x8 gldf(const unsigned short* p) {
    uint4 u = *(const uint4*)p;
    return __builtin_bit_cast(bf16x8, u);
}

// ---- prep kernel 1: weights f32 -> bf16 into d_ws ----
__global__ void wprep_kernel(const float* __restrict__ QKw, const float* __restrict__ Vw,
                             const float* __restrict__ Pw, unsigned short* __restrict__ wsb) {
    int i = blockIdx.x * 256 + threadIdx.x;        // 0 .. 147455
    if (i >= 147456) return;
    if (i < WS_WQKV_ELEMS) {
        int r = i / 192, c = i - r * 192;
        float v = (r < 384) ? QKw[r * 192 + c] : Vw[(r - 384) * 192 + c];
        wsb[i] = f2b(v);
    } else {
        int j = i - WS_WQKV_ELEMS;
        wsb[WS_WP_OFF_EL + j] = f2b(Pw[j]);
    }
}

// ---- prep kernel 2: rel-pos bias MLP table (225 x 6) ----
__global__ void bias_table_kernel(const float* __restrict__ Mw1, const float* __restrict__ Mb1,
                                  const float* __restrict__ Mw2, const float* __restrict__ Mb2,
                                  float* __restrict__ bias_out) {
    int t = blockIdx.x * 64 + threadIdx.x;
    if (t >= 225) return;
    int dyi = t / 15, dxi = t % 15;
    float dy = (float)(dyi - 7), dx = (float)(dxi - 7);
    float f0 = copysignf(log1pf(fabsf(dy)), dy);
    float f1 = copysignf(log1pf(fabsf(dx)), dx);
    float a0 = Mb2[0], a1 = Mb2[1], a2 = Mb2[2], a3 = Mb2[3], a4 = Mb2[4], a5 = Mb2[5];
    for (int u = 0; u < 256; ++u) {
        float hv = fmaxf(f0 * Mw1[u] + f1 * Mw1[256 + u] + Mb1[u], 0.0f);
        const float* w2 = Mw2 + u * 6;
        a0 = fmaf(hv, w2[0], a0); a1 = fmaf(hv, w2[1], a1);
        a2 = fmaf(hv, w2[2], a2); a3 = fmaf(hv, w2[3], a3);
        a4 = fmaf(hv, w2[4], a4); a5 = fmaf(hv, w2[5], a5);
    }
    float* bt = bias_out + t * 6;
    bt[0] = a0; bt[1] = a1; bt[2] = a2; bt[3] = a3; bt[4] = a4; bt[5] = a5;
}

__global__ __launch_bounds__(512, 4)
void fused_win_attn(const float* __restrict__ x,
                    const float* __restrict__ Vb, const float* __restrict__ QKb,
                    const float* __restrict__ Pb,
                    const unsigned short* __restrict__ wqkv,   // bf16 [576][192]
                    const unsigned short* __restrict__ wp,     // bf16 [192][192]
                    const float* __restrict__ bias_g,
                    float* __restrict__ out)
{
    extern __shared__ char smem[];
    const int t   = threadIdx.x;
    const int wv  = t >> 6;           // wave 0..7
    const int l15 = t & 15;
    const int l4  = (t >> 4) & 3;

    // XCD-aware swizzle: consecutive windows (sharing x cachelines) on same XCD.
    const int wid = ((blockIdx.x & 7) << 8) | (blockIdx.x >> 3);
    const int b   = wid >> 8;
    const int wy  = (wid >> 4) & 15;
    const int wx  = wid & 15;
    const int y0  = wy * 8, x0 = wx * 8;

    const f32x4 zz = {0.0f, 0.0f, 0.0f, 0.0f};

    // ---- P0: bias table -> LDS ----
    {
        float* bt = (float*)(smem + BTOFF);
        for (int i = t; i < 1350; i += 512) bt[i] = bias_g[i];
    }

    // ---- P1: load x window -> xs[tok][ch] (region A) ----
    {
        const float* xb = x + (size_t)b * 192 * 16384;
        #pragma unroll
        for (int i = 0; i < 6; ++i) {
            int idx = t + 512 * i;
            int c = idx >> 4, sub = idx & 15;
            int r = sub >> 1, hf = sub & 1;
            float4 v4 = *(const float4*)(xb + c * 16384 + (y0 + r) * 128 + x0 + hf * 4);
            int n0 = r * 8 + hf * 4;
            unsigned short sv[4] = {f2b(v4.x), f2b(v4.y), f2b(v4.z), f2b(v4.w)};
            #pragma unroll
            for (int e = 0; e < 4; ++e) {
                int n = n0 + e;
                *(unsigned short*)(smem + RA + ((n * 384 + c * 2) ^ ((n & 7) << 4))) = sv[e];
            }
        }
    }
    __syncthreads();

    // ---- P2: qkv GEMM. wave (wcol, wrow): cols [48*wcol,+48) per tensor, toks [32*wrow,+32) ----
    const int wcol = wv & 3, wrow = wv >> 2;
    unsigned int vp[3][2][2];          // packed v held across conv: [j][mtl][tok-pair]
    {
        // hoist A fragments, then barrier -> xs region becomes free
        bf16x8 afr[6][2];
        #pragma unroll
        for (int ks = 0; ks < 6; ++ks)
            #pragma unroll
            for (int mtl = 0; mtl < 2; ++mtl) {
                int row = (wrow * 2 + mtl) * 16 + l15;
                afr[ks][mtl] = ldsf(smem + RA + ((row * 384 + ks * 64 + l4 * 16) ^ ((row & 7) << 4)));
            }
        __syncthreads();

        auto gemm3 = [&](int obase, f32x4 acc[3][2]) {
            bf16x8 bw[3][6];
            #pragma unroll
            for (int j = 0; j < 3; ++j) {
                const unsigned short* wr = wqkv + (size_t)(obase + j * 16 + l15) * 192 + l4 * 8;
                #pragma unroll
                for (int ks = 0; ks < 6; ++ks) bw[j][ks] = gldf(wr + ks * 32);
            }
            #pragma unroll
            for (int j = 0; j < 3; ++j) { acc[j][0] = zz; acc[j][1] = zz; }
            #pragma unroll
            for (int ks = 0; ks < 6; ++ks)
                #pragma unroll
                for (int j = 0; j < 3; ++j)
                    #pragma unroll
                    for (int mtl = 0; mtl < 2; ++mtl)
                        acc[j][mtl] = __builtin_amdgcn_mfma_f32_16x16x32_bf16(afr[ks][mtl], bw[j][ks], acc[j][mtl], 0, 0, 0);
        };

        // chunk 0: q -> region A (scaled)
        {
            f32x4 acc[3][2];
            gemm3(wcol * 48, acc);
            #pragma unroll
            for (int j = 0; j < 3; ++j) {
                int och = wcol * 48 + j * 16 + l15;
                float bv = QKb[och];
                #pragma unroll
                for (int mtl = 0; mtl < 2; ++mtl)
                    #pragma unroll
                    for (int rr = 0; rr < 4; ++rr) {
                        int tok = (wrow * 2 + mtl) * 16 + l4 * 4 + rr;
                        *(unsigned short*)(smem + RA + ((tok * 384 + och * 2) ^ ((tok & 7) << 4)))
                            = f2b((acc[j][mtl][rr] + bv) * SCALEQ);
                    }
            }
        }
        // chunk 1: k -> region B
        {
            f32x4 acc[3][2];
            gemm3(192 + wcol * 48, acc);
            #pragma unroll
            for (int j = 0; j < 3; ++j) {
                int ch = wcol * 48 + j * 16 + l15;
                float bv = QKb[192 + ch];
                #pragma unroll
                for (int mtl = 0; mtl < 2; ++mtl)
                    #pragma unroll
                    for (int rr = 0; rr < 4; ++rr) {
                        int tok = (wrow * 2 + mtl) * 16 + l4 * 4 + rr;
                        *(unsigned short*)(smem + RB + ((tok * 384 + ch * 2) ^ ((tok & 7) << 4)))
                            = f2b(acc[j][mtl][rr] + bv);
                    }
            }
        }
        // chunk 2: v -> registers (packed bf16 pairs along tok)
        {
            f32x4 acc[3][2];
            gemm3(384 + wcol * 48, acc);
            #pragma unroll
            for (int j = 0; j < 3; ++j) {
                int ch = wcol * 48 + j * 16 + l15;
                float bv = Vb[ch];
                #pragma unroll
                for (int mtl = 0; mtl < 2; ++mtl) {
                    vp[j][mtl][0] = pk2(acc[j][mtl][0] + bv, acc[j][mtl][1] + bv);
                    vp[j][mtl][1] = pk2(acc[j][mtl][2] + bv, acc[j][mtl][3] + bv);
                }
            }
        }
    }
    __syncthreads();

    // ---- P3: 8x8 circular conv q(A) x k(B) -> o(C). 384 threads, f32x2 packed ----
    if (t < 384) {
        const int rn = t / 48, cc = t % 48;
        const int c0b = cc * 8;               // byte offset of 4-ch chunk
        f32x2 acc[8][2];
        #pragma unroll
        for (int cn = 0; cn < 8; ++cn) {
            acc[cn][0] = (f32x2){0.0f, 0.0f};
            acc[cn][1] = (f32x2){0.0f, 0.0f};
        }
        #pragma unroll
        for (int kh = 0; kh < 2; ++kh) {
            uint2 karr[32];
            #pragma unroll
            for (int m = 0; m < 32; ++m) {
                int row = kh * 32 + m;
                karr[m] = *(const uint2*)(smem + RB + ((row * 384 + c0b) ^ ((row & 7) << 4)));
            }
            #pragma unroll
            for (int mrl = 0; mrl < 4; ++mrl) {
                const int mr = kh * 4 + mrl;
                f32x2 kf[8][2];
                #pragma unroll
                for (int mc = 0; mc < 8; ++mc) {
                    uint2 kv = karr[mrl * 8 + mc];
                    kf[mc][0] = b2x2(kv.x); kf[mc][1] = b2x2(kv.y);
                }
                const int npr = (rn - mr) & 7;
                #pragma unroll
                for (int npc = 0; npc < 8; ++npc) {
                    int np = npr * 8 + npc;
                    uint2 qv = *(const uint2*)(smem + RA + ((np * 384 + c0b) ^ ((np & 7) << 4)));
                    f32x2 qf0 = b2x2(qv.x), qf1 = b2x2(qv.y);
                    #pragma unroll
                    for (int mc = 0; mc < 8; ++mc) {
                        int cn = (npc + mc) & 7;
                        acc[cn][0] = qf0 * kf[mc][0] + acc[cn][0];
                        acc[cn][1] = qf1 * kf[mc][1] + acc[cn][1];
                    }
                }
            }
        }
        #pragma unroll
        for (int cn = 0; cn < 8; ++cn) {
            int n = rn * 8 + cn;
            uint2 pk;
            pk.x = pk2(acc[cn][0][0], acc[cn][0][1]);
            pk.y = pk2(acc[cn][1][0], acc[cn][1][1]);
            *(uint2*)(smem + RC + ((n * 384 + c0b) ^ ((n & 7) << 4))) = pk;
        }
    }
    __syncthreads();

    // ---- P3b: write held v regs -> v_n (A, over q) and v_t (B, over k) ----
    {
        #pragma unroll
        for (int j = 0; j < 3; ++j) {
            int ch = wcol * 48 + j * 16 + l15;
            #pragma unroll
            for (int mtl = 0; mtl < 2; ++mtl)
                #pragma unroll
                for (int pp = 0; pp < 2; ++pp) {
                    unsigned int pk = vp[j][mtl][pp];
                    int tok0 = (wrow * 2 + mtl) * 16 + l4 * 4 + pp * 2;
                    // v_t[ch][tok]: pair is tok-contiguous -> one u32 store
                    *(unsigned int*)(smem + RB + ((ch * 128 + tok0 * 2) ^ ((ch & 7) << 4))) = pk;
                    // v_n[tok][ch]: two b16 stores
                    *(unsigned short*)(smem + RA + ((tok0 * 384 + ch * 2) ^ ((tok0 & 7) << 4)))
                        = (unsigned short)(pk & 0xffffu);
                    *(unsigned short*)(smem + RA + (((tok0 + 1) * 384 + ch * 2) ^ (((tok0 + 1) & 7) << 4)))
                        = (unsigned short)(pk >> 16);
                }
        }
    }
    __syncthreads();

    // ---- P4: S^T = mfma(v_n, o) + bias^T, softmax over m, P packed in regs ----
    unsigned int pv[3][4][2];              // [unit][mt][pair]: P[n=l15-col][m]
    {
        const float* bt = (const float*)(smem + BTOFF);
        #pragma unroll
        for (int i = 0; i < 3; ++i) {
            int u = wv * 3 + i;
            int h = u >> 2, nt = u & 3;
            int brow = nt * 16 + l15;
            bf16x8 ofr = ldsf(smem + RC + ((brow * 384 + h * 64 + l4 * 16) ^ ((brow & 7) << 4)));
            int n = nt * 16 + l15;
            int nr = n >> 3, nc = n & 7;
            float s[4][4];
            #pragma unroll
            for (int mt = 0; mt < 4; ++mt) {
                int arow = mt * 16 + l15;
                bf16x8 vfr = ldsf(smem + RA + ((arow * 384 + h * 64 + l4 * 16) ^ ((arow & 7) << 4)));
                f32x4 a = __builtin_amdgcn_mfma_f32_16x16x32_bf16(vfr, ofr, zz, 0, 0, 0);
                #pragma unroll
                for (int rr = 0; rr < 4; ++rr) {
                    int m = mt * 16 + l4 * 4 + rr;
                    int dy = nr - (m >> 3) + 7, dx = nc - (m & 7) + 7;
                    s[mt][rr] = a[rr] + bt[(dy * 15 + dx) * 6 + h];
                }
            }
            float m0 = s[0][0];
            #pragma unroll
            for (int mt = 0; mt < 4; ++mt)
                #pragma unroll
                for (int rr = 0; rr < 4; ++rr) m0 = fmaxf(m0, s[mt][rr]);
            m0 = fmaxf(m0, __shfl_xor(m0, 16));
            m0 = fmaxf(m0, __shfl_xor(m0, 32));
            float sm = 0.0f;
            #pragma unroll
            for (int mt = 0; mt < 4; ++mt)
                #pragma unroll
                for (int rr = 0; rr < 4; ++rr) {
                    float p = __expf(s[mt][rr] - m0);
                    s[mt][rr] = p; sm += p;
                }
            sm += __shfl_xor(sm, 16);
            sm += __shfl_xor(sm, 32);
            float inv = 1.0f / sm;
            #pragma unroll
            for (int mt = 0; mt < 4; ++mt) {
                pv[i][mt][0] = pk2(s[mt][0] * inv, s[mt][1] * inv);
                pv[i][mt][1] = pk2(s[mt][2] * inv, s[mt][3] * inv);
            }
        }
    }
    __syncthreads();   // all units done reading o -> region C reusable

    // ---- P5: Y = mfma(P, v_t) -> y (C, over o) ----
    {
        #pragma unroll
        for (int i = 0; i < 3; ++i) {
            int u = wv * 3 + i;
            int h = u >> 2, nt = u & 3;
            // build A-fragments from packed P: element j of frag ks is
            // P[n=nt*16+l15][m=ks*32+l4*8+j], held by lane srcl4=(l4&1)*2+(j>>2)
            // in register pv[i][2ks + (l4_dst>>1)][(j>>1)&1]. Two pulls + dst
            // select (one shuffle can't serve l4=0 and l4=2 from the same src).
            bf16x8 pafr[2];
            #pragma unroll
            for (int ks = 0; ks < 2; ++ks) {
                unsigned int au[4];
                #pragma unroll
                for (int p = 0; p < 4; ++p) {
                    int srcl4 = (2 * l4 + (p >> 1)) & 3;
                    int src = srcl4 * 16 + l15;
                    unsigned int v0 = (unsigned int)__shfl((int)pv[i][2 * ks][p & 1], src, 64);
                    unsigned int v1 = (unsigned int)__shfl((int)pv[i][2 * ks + 1][p & 1], src, 64);
                    au[p] = (l4 & 2) ? v1 : v0;
                }
                uint4 u4 = {au[0], au[1], au[2], au[3]};
                pafr[ks] = __builtin_bit_cast(bf16x8, u4);
            }
            f32x4 acc[2];
            acc[0] = zz; acc[1] = zz;
            #pragma unroll
            for (int dt = 0; dt < 2; ++dt)
                #pragma unroll
                for (int ks = 0; ks < 2; ++ks) {
                    int drow = h * 32 + dt * 16 + l15;
                    bf16x8 vtf = ldsf(smem + RB + ((drow * 128 + ks * 64 + l4 * 16) ^ ((drow & 7) << 4)));
                    acc[dt] = __builtin_amdgcn_mfma_f32_16x16x32_bf16(pafr[ks], vtf, acc[dt], 0, 0, 0);
                }
            #pragma unroll
            for (int dt = 0; dt < 2; ++dt)
                #pragma unroll
                for (int rr = 0; rr < 4; ++rr) {
                    int tok = nt * 16 + l4 * 4 + rr;
                    int ch  = h * 32 + dt * 16 + l15;
                    *(unsigned short*)(smem + RC + ((tok * 384 + ch * 2) ^ ((tok & 7) << 4))) = f2b(acc[dt][rr]);
                }
        }
    }
    __syncthreads();

    // ---- P6: proj OUT^T[oc][tok] = Pw . y^T. wave (wc, wr) ----
    {
        const int wc = wv & 3, wr = wv >> 2;
        bf16x8 wfr[3][6];
        #pragma unroll
        for (int jt = 0; jt < 3; ++jt) {
            int oc = wc * 48 + jt * 16;
            const unsigned short* wr_ = wp + (size_t)(oc + l15) * 192 + l4 * 8;
            #pragma unroll
            for (int ks = 0; ks < 6; ++ks) wfr[jt][ks] = gldf(wr_ + ks * 32);
        }
        f32x4 acc[3][2];
        #pragma unroll
        for (int jt = 0; jt < 3; ++jt) { acc[jt][0] = zz; acc[jt][1] = zz; }

        #pragma unroll
        for (int ks = 0; ks < 6; ++ks) {
            bf16x8 bfr[2];
            #pragma unroll
            for (int ntl = 0; ntl < 2; ++ntl) {
                int tok = (wr * 2 + ntl) * 16 + l15;
                bfr[ntl] = ldsf(smem + RC + ((tok * 384 + ks * 64 + l4 * 16) ^ ((tok & 7) << 4)));
            }
            #pragma unroll
            for (int jt = 0; jt < 3; ++jt)
                #pragma unroll
                for (int ntl = 0; ntl < 2; ++ntl)
                    acc[jt][ntl] = __builtin_amdgcn_mfma_f32_16x16x32_bf16(wfr[jt][ks], bfr[ntl], acc[jt][ntl], 0, 0, 0);
        }
        #pragma unroll
        for (int jt = 0; jt < 3; ++jt)
            #pragma unroll
            for (int rr = 0; rr < 4; ++rr) {
                int oc = wc * 48 + jt * 16 + l4 * 4 + rr;
                float pb = Pb[oc];
                float* obase = out + (size_t)(b * 192 + oc) * 16384;
                #pragma unroll
                for (int ntl = 0; ntl < 2; ++ntl) {
                    int tok = (wr * 2 + ntl) * 16 + l15;
                    obase[(y0 + (tok >> 3)) * 128 + x0 + (tok & 7)] = acc[jt][ntl][rr] + pb;
                }
            }
    }
}

extern "C" void kernel_launch(void* const* d_in, const int* in_sizes, int n_in,
                              void* d_out, int out_size, void* d_ws, size_t ws_size,
                              hipStream_t stream) {
    const float* x   = (const float*)d_in[0];
    const float* Vw  = (const float*)d_in[1];
    const float* Vb  = (const float*)d_in[2];
    const float* QKw = (const float*)d_in[3];
    const float* QKb = (const float*)d_in[4];
    const float* Pw  = (const float*)d_in[5];
    const float* Pb  = (const float*)d_in[6];
    const float* Mw1 = (const float*)d_in[7];
    const float* Mb1 = (const float*)d_in[8];
    const float* Mw2 = (const float*)d_in[9];
    const float* Mb2 = (const float*)d_in[10];
    float* outp = (float*)d_out;

    unsigned short* wsb  = (unsigned short*)d_ws;              // bf16 weights
    float* biasw = (float*)((char*)d_ws + WS_BT_OFF_B);        // bias table

    wprep_kernel<<<dim3(576), dim3(256), 0, stream>>>(QKw, Vw, Pw, wsb);
    bias_table_kernel<<<dim3(4), dim3(64), 0, stream>>>(Mw1, Mb1, Mw2, Mb2, biasw);

    (void)hipFuncSetAttribute((const void*)fused_win_attn,
                              hipFuncAttributeMaxDynamicSharedMemorySize, LDS_BYTES);
    fused_win_attn<<<dim3(2048), dim3(512), LDS_BYTES, stream>>>(
        x, Vb, QKb, Pb, wsb, wsb + WS_WP_OFF_EL, biasw, outp);
}